// Round 3
// baseline (673.490 us; speedup 1.0000x reference)
//
#include <hip/hip_runtime.h>
#include <hip/hip_cooperative_groups.h>
#include <stdint.h>

namespace cg = cooperative_groups;

typedef unsigned short u16;
typedef __bf16 bf16x8 __attribute__((ext_vector_type(8)));
typedef float f32x4 __attribute__((ext_vector_type(4)));

#define DEVINL __device__ __forceinline__

DEVINL u16 f2bf(float f){
  uint32_t x = __float_as_uint(f);
  uint32_t r = (x + 0x7fffu + ((x >> 16) & 1u)) >> 16;
  return (u16)r;
}

DEVINL float wave_sum(float v){
#pragma unroll
  for (int off = 32; off; off >>= 1) v += __shfl_xor(v, off);
  return v;
}

DEVINL float dot8(float4 a0, float4 a1, float4 b0, float4 b1){
  return a0.x*b0.x + a0.y*b0.y + a0.z*b0.z + a0.w*b0.w
       + a1.x*b1.x + a1.y*b1.y + a1.z*b1.z + a1.w*b1.w;
}

DEVINL void gload_lds16(const void* g, void* l){
  __builtin_amdgcn_global_load_lds(
      (const __attribute__((address_space(1))) uint32_t*)g,
      (__attribute__((address_space(3))) uint32_t*)l, 16, 0, 0);
}

// 8 m-rows x 4 n-cols f32 dot-GEMM unit; K % 256 == 0.
DEVINL void gemm_unit(const float* __restrict__ A, int lda,
                      const float* __restrict__ W, int ldw,
                      const float* __restrict__ bias,
                      float* __restrict__ C, int ldc,
                      int m0, int n0, int nmax, int K, bool relu, int lane)
{
  const float* wrow[4];
#pragma unroll
  for (int q = 0; q < 4; q++){
    int n = n0 + q; if (n >= nmax) n = nmax - 1;
    wrow[q] = W + (size_t)n * ldw + lane * 4;
  }
  const float* arow = A + (size_t)m0 * lda + lane * 4;
  float acc[8][4] = {};
  for (int kc = 0; kc < K; kc += 256){
    float4 w4[4];
#pragma unroll
    for (int q = 0; q < 4; q++) w4[q] = *(const float4*)(wrow[q] + kc);
#pragma unroll
    for (int r = 0; r < 8; r++){
      float4 a4 = *(const float4*)(arow + (size_t)r * lda + kc);
#pragma unroll
      for (int q = 0; q < 4; q++)
        acc[r][q] = fmaf(w4[q].x, a4.x, fmaf(w4[q].y, a4.y,
                    fmaf(w4[q].z, a4.z, fmaf(w4[q].w, a4.w, acc[r][q]))));
    }
  }
#pragma unroll
  for (int r = 0; r < 8; r++){
#pragma unroll
    for (int q = 0; q < 4; q++){
      float v = wave_sum(acc[r][q]);
      const int n = n0 + q;
      if (lane == 0 && n < nmax){
        float o = v + (bias ? bias[n] : 0.f);
        if (relu) o = fmaxf(o, 0.f);
        C[(size_t)(m0 + r) * ldc + n] = o;
      }
    }
  }
}

struct MP {
  const float *pf,*Wp,*bp,*We,*be,*Wsem,*bsem,*Wel,*bel,*Wee,*bee,*Wop,*bop,*Wc,*bc,*Wc2,*bc2;
  float *out_cf,*out_sem,*out_ex,*out_eel;
  u16 *elb, *wfb;
  float *feats,*P,*Q,*wsA,*wsB,*wsA2,*wsB2,*wsH,*exw;
  int *flag;
};

__global__ __launch_bounds__(256, 2) void mega(MP p)
{
  __shared__ u16 tile[2][2][8192];   // 64 KB: [buf][A/B][128 rows x 64 cols bf16]
  __shared__ float smax[2][128];
  cg::grid_group grid = cg::this_grid();
  const int tid = threadIdx.x, lane = tid & 63, wid = tid >> 6;
  const int bid = blockIdx.x, NB = gridDim.x;
  const int gw = bid * 4 + wid, NW = NB * 4;

  // ================= P1: flag init + cf + wconv ===========================
  if (gw == 0 && lane == 0) *p.flag = 0;
  {
    const float4* pp = (const float4*)p.pf;
    float4 p0 = pp[lane*2], p1 = pp[lane*2+1];
    for (int n = gw*2; n < 65536; n += NW*2){
      const float4* r0 = (const float4*)(p.Wp + (size_t)n*512);
      const float4* r1 = (const float4*)(p.Wp + (size_t)(n+1)*512);
      float4 a0 = r0[lane*2], a1 = r0[lane*2+1];
      float4 b0 = r1[lane*2], b1 = r1[lane*2+1];
      float v0 = wave_sum(dot8(a0, a1, p0, p1));
      float v1 = wave_sum(dot8(b0, b1, p0, p1));
      if (lane == 0){
        p.feats[(size_t)(n >> 9)*1536 + (n & 511)] = fmaxf(v0 + p.bp[n], 0.f);
        const int n1 = n + 1;
        p.feats[(size_t)(n1 >> 9)*1536 + (n1 & 511)] = fmaxf(v1 + p.bp[n1], 0.f);
      }
    }
    for (int t = bid*256 + tid; t < 65536; t += NB*256){
      const int e = t * 8;
      const int it = e >> 18;
      const int rem = e & 262143;
      const int h = rem >> 9, k = rem & 511;
      const float* src = p.Wop + (size_t)it*788480 + (size_t)h*1540 + 1024 + k;
      float4 v0 = ((const float4*)src)[0];
      float4 v1 = ((const float4*)src)[1];
      union { u16 u[8]; uint4 q4; } o;
      o.u[0]=f2bf(v0.x); o.u[1]=f2bf(v0.y); o.u[2]=f2bf(v0.z); o.u[3]=f2bf(v0.w);
      o.u[4]=f2bf(v1.x); o.u[5]=f2bf(v1.y); o.u[6]=f2bf(v1.z); o.u[7]=f2bf(v1.w);
      *(uint4*)(p.wfb + e) = o.q4;
    }
  }
  __threadfence(); grid.sync();

  // ================= P2: P/Q gemm + it0 A/B gemm + exists =================
  for (int u = gw; u < 8208; u += NW){
    if (u < 8192){
      const int g  = u >> 12;
      const int m0 = ((u >> 8) & 15) * 8;
      const int n0 = (u & 255) * 4;
      if (g == 0){
        if (n0 < 512) gemm_unit(p.feats, 1536, p.Wel,       1024, p.bel, p.P, 512, m0, n0,       512, 512, false, lane);
        else          gemm_unit(p.feats, 1536, p.Wel + 512, 1024, 0,     p.Q, 512, m0, n0 - 512, 512, 512, false, lane);
      } else {
        if (n0 < 512) gemm_unit(p.feats, 1536, p.Wop,       1540, p.bop, p.wsA, 512, m0, n0,       512, 512, false, lane);
        else          gemm_unit(p.feats, 1536, p.Wop + 512, 1540, 0,     p.wsB, 512, m0, n0 - 512, 512, 512, false, lane);
      }
    } else {
      const int m0 = (u - 8192) * 8;
      const float4* w = (const float4*)p.We;
      float4 w0 = w[lane*2], w1 = w[lane*2+1];
#pragma unroll
      for (int r = 0; r < 8; r++){
        const float4* a = (const float4*)(p.feats + (size_t)(m0 + r)*1536);
        float v = wave_sum(dot8(a[lane*2], a[lane*2+1], w0, w1));
        if (lane == 0){
          float o = v + p.be[0];
          p.out_ex[m0 + r] = o;
          p.exw[m0 + r] = o;
        }
      }
    }
  }
  __threadfence(); grid.sync();

  // ================= P3: el (bf16) + eel + has_edges ======================
  {
    bool wf = false;
    const float4 be4 = *(const float4*)p.bee;
    for (int row = gw; row < 16384; row += NW){
      const int i = row >> 7, j = row & 127;
      const int k0 = lane << 3;
      float4 p0 = *(const float4*)(p.P + (size_t)i*512 + k0);
      float4 p1 = *(const float4*)(p.P + (size_t)i*512 + k0 + 4);
      float4 q0 = *(const float4*)(p.Q + (size_t)j*512 + k0);
      float4 q1 = *(const float4*)(p.Q + (size_t)j*512 + k0 + 4);
      float e[8];
      e[0]=fmaxf(p0.x+q0.x,0.f); e[1]=fmaxf(p0.y+q0.y,0.f);
      e[2]=fmaxf(p0.z+q0.z,0.f); e[3]=fmaxf(p0.w+q0.w,0.f);
      e[4]=fmaxf(p1.x+q1.x,0.f); e[5]=fmaxf(p1.y+q1.y,0.f);
      e[6]=fmaxf(p1.z+q1.z,0.f); e[7]=fmaxf(p1.w+q1.w,0.f);
      union { u16 u[8]; uint4 q4; } o;
#pragma unroll
      for (int c = 0; c < 8; c++) o.u[c] = f2bf(e[c]);
      *(uint4*)(p.elb + (size_t)row*512 + k0) = o.q4;
      float acc[4];
#pragma unroll
      for (int t = 0; t < 4; t++){
        float4 w0 = *(const float4*)(p.Wee + t*512 + k0);
        float4 w1 = *(const float4*)(p.Wee + t*512 + k0 + 4);
        float a = e[0]*w0.x + e[1]*w0.y + e[2]*w0.z + e[3]*w0.w
                + e[4]*w1.x + e[5]*w1.y + e[6]*w1.z + e[7]*w1.w;
        acc[t] = wave_sum(a);
      }
      float4 r = make_float4(acc[0]+be4.x, acc[1]+be4.y, acc[2]+be4.z, acc[3]+be4.w);
      if (lane == 0) *(float4*)(p.out_eel + (size_t)row*4) = r;
      if ((p.exw[i] > 0.f) && (p.exw[j] > 0.f) &&
          (r.x > 0.f || r.y > 0.f || r.z > 0.f || r.w > 0.f)) wf = true;
    }
    if (wf && lane == 0) atomicOr(p.flag, 1);
  }
  __threadfence(); grid.sync();

  // ================= iterations ===========================================
  const int wr = wid >> 1, wc = wid & 1;
  const int slog = lane >> 4;
  for (int it = 0; it < 2; it++){
    const float* Aterm = it ? p.wsA2 : p.wsA;
    const float* Bterm = it ? p.wsB2 : p.wsB;
    const u16*   wslab = p.wfb + (size_t)it*262144;
    const float* Wit   = p.Wop + (size_t)it*788480;
    const int fl = __hip_atomic_load(p.flag, __ATOMIC_RELAXED, __HIP_MEMORY_SCOPE_AGENT);

    for (int vb = bid; vb < 512; vb += NB){
      __syncthreads();
      const int i   = ((vb >> 5) << 3) | (vb & 7);
      const int hc0 = ((vb >> 3) & 3) << 7;

      const u16* srcA[4]; const u16* srcB[4]; int dst[4];
#pragma unroll
      for (int rd = 0; rd < 4; rd++){
        int c = tid + 256*rd;
        int r = c >> 3, s = c & 7;
        int cb = s ^ (r & 7);
        srcA[rd] = p.elb + (size_t)(i*128 + r)*512 + (cb << 3);
        srcB[rd] = wslab + (size_t)(hc0 + r)*512 + (cb << 3);
        dst[rd]  = c << 3;
      }
      int byteA[2][4], byteB[2][4];
#pragma unroll
      for (int k2 = 0; k2 < 2; k2++){
#pragma unroll
        for (int f = 0; f < 4; f++){
          int ra = wr*64 + f*16 + (lane & 15);
          byteA[k2][f] = ra*128 + (((k2*4 + slog) ^ (ra & 7)) << 4);
          int rb = wc*64 + f*16 + (lane & 15);
          byteB[k2][f] = rb*128 + (((k2*4 + slog) ^ (rb & 7)) << 4);
        }
      }
      f32x4 acc[4][4] = {};
      auto stage = [&](int buf, int ks){
        const int k0 = ks << 6;
        u16* dA = &tile[buf][0][0];
        u16* dB = &tile[buf][1][0];
#pragma unroll
        for (int rd = 0; rd < 4; rd++){
          gload_lds16(srcA[rd] + k0, dA + dst[rd]);
          gload_lds16(srcB[rd] + k0, dB + dst[rd]);
        }
      };
      stage(0, 0);
      __syncthreads();
      for (int ks = 0; ks < 8; ks++){
        const int cur = ks & 1;
        if (ks < 7) stage(cur ^ 1, ks + 1);
        const char* baseA = (const char*)&tile[cur][0][0];
        const char* baseB = (const char*)&tile[cur][1][0];
#pragma unroll
        for (int k2 = 0; k2 < 2; k2++){
          bf16x8 a[4], b[4];
#pragma unroll
          for (int f = 0; f < 4; f++){
            a[f] = *(const bf16x8*)(baseA + byteA[k2][f]);
            b[f] = *(const bf16x8*)(baseB + byteB[k2][f]);
          }
#pragma unroll
          for (int fa = 0; fa < 4; fa++)
#pragma unroll
            for (int fb = 0; fb < 4; fb++)
              acc[fa][fb] = __builtin_amdgcn_mfma_f32_16x16x32_bf16(a[fa], b[fb], acc[fa][fb], 0, 0, 0);
        }
        __syncthreads();
      }

      // epilogue: msg = relu(pre + e0*Wt), masked max over (j,t)
      const bool mi = p.exw[i] > 0.f;
      float Ah[4]; float4 wt[4]; int hg[4];
#pragma unroll
      for (int fb = 0; fb < 4; fb++){
        hg[fb] = hc0 + wc*64 + fb*16 + (lane & 15);
        Ah[fb] = Aterm[i*512 + hg[fb]];
        wt[fb] = *(const float4*)(Wit + (size_t)hg[fb]*1540 + 1536);
      }
      float tm[4] = {0.f, 0.f, 0.f, 0.f};
#pragma unroll
      for (int fa = 0; fa < 4; fa++){
        const int j0 = wr*64 + fa*16 + slog*4;
#pragma unroll
        for (int r = 0; r < 4; r++){
          const int j = j0 + r;
          float4 e4 = *(const float4*)(p.out_eel + (size_t)(i*128 + j)*4);
          const bool mj = mi && (p.exw[j] > 0.f);
          const bool c0 = mj && (e4.x > 0.f), c1 = mj && (e4.y > 0.f);
          const bool c2 = mj && (e4.z > 0.f), c3 = mj && (e4.w > 0.f);
#pragma unroll
          for (int fb = 0; fb < 4; fb++){
            float val = acc[fa][fb][r] + Ah[fb] + Bterm[(size_t)j*512 + hg[fb]];
            if (c0) tm[fb] = fmaxf(tm[fb], val + e4.x*wt[fb].x);
            if (c1) tm[fb] = fmaxf(tm[fb], val + e4.y*wt[fb].y);
            if (c2) tm[fb] = fmaxf(tm[fb], val + e4.z*wt[fb].z);
            if (c3) tm[fb] = fmaxf(tm[fb], val + e4.w*wt[fb].w);
          }
        }
      }
#pragma unroll
      for (int fb = 0; fb < 4; fb++){
        float v = tm[fb];
        v = fmaxf(v, __shfl_xor(v, 16));
        v = fmaxf(v, __shfl_xor(v, 32));
        if (lane < 16) smax[wr][wc*64 + fb*16 + lane] = v;
      }
      __syncthreads();
      if (tid < 128){
        const float v = fmaxf(smax[0][tid], smax[1][tid]);
        const int hgl = hc0 + tid;
        const float prev = p.feats[(size_t)i*1536 + it*512 + hgl];
        p.feats[(size_t)i*1536 + 512 + it*512 + hgl] = fl ? v : prev;
      }
    }
    __threadfence(); grid.sync();

    if (it == 0){
      const float* W1 = p.Wop + 788480;
      for (int u = gw; u < 4096; u += NW){
        const int m0 = ((u >> 8) & 15) * 8;
        const int n0 = (u & 255) * 4;
        if (n0 < 512) gemm_unit(p.feats + 512, 1536, W1,       1540, p.bop + 512, p.wsA2, 512, m0, n0,       512, 512, false, lane);
        else          gemm_unit(p.feats + 512, 1536, W1 + 512, 1540, 0,           p.wsB2, 512, m0, n0 - 512, 512, 512, false, lane);
      }
      __threadfence(); grid.sync();
    }
  }

  // ================= P7: head h = relu(feats @ Wc.T + bc) =================
  for (int u = gw; u < 2048; u += NW){
    const int m0 = (u >> 7) * 8;
    const int n0 = (u & 127) * 4;
    gemm_unit(p.feats, 1536, p.Wc, 1536, p.bc, p.wsH, 512, m0, n0, 512, 1536, true, lane);
  }
  __threadfence(); grid.sync();

  // ================= P8: sem + out_cf =====================================
  for (int u = gw; u < 2256; u += NW){
    if (u < 208){
      const int m0 = (u / 13) * 8;
      const int n0 = (u % 13) * 4;
      gemm_unit(p.wsH, 512, p.Wsem, 512, p.bsem, p.out_sem, 50, m0, n0, 50, 512, false, lane);
    } else {
      const int v = u - 208;
      const int m0 = (v >> 7) * 8;
      const int n0 = (v & 127) * 4;
      gemm_unit(p.wsH, 512, p.Wc2, 512, p.bc2, p.out_cf, 512, m0, n0, 512, 512, true, lane);
    }
  }
}

// ---------------------------------------------------------------------------
extern "C" void kernel_launch(void* const* d_in, const int* in_sizes, int n_in,
                              void* d_out, int out_size, void* d_ws, size_t ws_size,
                              hipStream_t stream)
{
  MP p;
  p.pf   = (const float*)d_in[0];
  p.Wp   = (const float*)d_in[1];
  p.bp   = (const float*)d_in[2];
  p.We   = (const float*)d_in[3];
  p.be   = (const float*)d_in[4];
  p.Wsem = (const float*)d_in[5];
  p.bsem = (const float*)d_in[6];
  p.Wel  = (const float*)d_in[7];
  p.bel  = (const float*)d_in[8];
  p.Wee  = (const float*)d_in[9];
  p.bee  = (const float*)d_in[10];
  p.Wop  = (const float*)d_in[11];
  p.bop  = (const float*)d_in[12];
  p.Wc   = (const float*)d_in[13];
  p.bc   = (const float*)d_in[14];
  p.Wc2  = (const float*)d_in[15];
  p.bc2  = (const float*)d_in[16];

  float* out = (float*)d_out;
  p.out_cf  = out;
  p.out_sem = out + 65536;
  p.out_ex  = out + 71936;
  p.out_eel = out + 72064;

  char* ws = (char*)d_ws;
  p.elb   = (u16*)ws;                       // 16 MB
  p.feats = (float*)(ws + 16777216);        // [128][1536]
  p.P     = p.feats + 196608;
  p.Q     = p.P + 65536;
  p.wsA   = p.Q + 65536;
  p.wsB   = p.wsA + 65536;
  p.wsA2  = p.wsB + 65536;
  p.wsB2  = p.wsA2 + 65536;
  p.wsH   = p.wsB2 + 65536;
  p.exw   = p.wsH + 65536;                  // [128]
  p.flag  = (int*)(p.exw + 160);            // own cache line
  p.wfb   = (u16*)(p.flag + 64);            // [2][512][512] bf16

  int maxb = 0;
  hipOccupancyMaxActiveBlocksPerMultiprocessor(&maxb, mega, 256, 0);
  if (maxb < 1) maxb = 1;
  int nblk = maxb * 256;
  if (nblk > 512) nblk = 512;

  void* args[] = { (void*)&p };
  hipLaunchCooperativeKernel(mega, dim3(nblk), dim3(256), args, 0, stream);
}

// Round 4
// 219.682 us; speedup vs baseline: 3.0658x; 3.0658x over previous
//
#include <hip/hip_runtime.h>
#include <stdint.h>

typedef unsigned short u16;
typedef __bf16 bf16x8 __attribute__((ext_vector_type(8)));
typedef float f32x4 __attribute__((ext_vector_type(4)));

#define DEVINL __device__ __forceinline__

DEVINL u16 f2bf(float f){
  uint32_t x = __float_as_uint(f);
  uint32_t r = (x + 0x7fffu + ((x >> 16) & 1u)) >> 16;
  return (u16)r;
}

DEVINL float wave_sum(float v){
#pragma unroll
  for (int off = 32; off; off >>= 1) v += __shfl_xor(v, off);
  return v;
}

DEVINL float dot8(float4 a0, float4 a1, float4 b0, float4 b1){
  return a0.x*b0.x + a0.y*b0.y + a0.z*b0.z + a0.w*b0.w
       + a1.x*b1.x + a1.y*b1.y + a1.z*b1.z + a1.w*b1.w;
}

DEVINL void gload_lds16(const void* g, void* l){
  __builtin_amdgcn_global_load_lds(
      (const __attribute__((address_space(1))) uint32_t*)g,
      (__attribute__((address_space(3))) uint32_t*)l, 16, 0, 0);
}

// 8 m-rows x 4 n-cols f32 dot-GEMM unit; K % 256 == 0.
DEVINL void gemm_unit(const float* __restrict__ A, int lda,
                      const float* __restrict__ W, int ldw,
                      const float* __restrict__ bias,
                      float* __restrict__ C, int ldc,
                      int m0, int n0, int nmax, int K, bool relu, int lane)
{
  const float* wrow[4];
#pragma unroll
  for (int q = 0; q < 4; q++){
    int n = n0 + q; if (n >= nmax) n = nmax - 1;
    wrow[q] = W + (size_t)n * ldw + lane * 4;
  }
  const float* arow = A + (size_t)m0 * lda + lane * 4;
  float acc[8][4] = {};
  for (int kc = 0; kc < K; kc += 256){
    float4 w4[4];
#pragma unroll
    for (int q = 0; q < 4; q++) w4[q] = *(const float4*)(wrow[q] + kc);
#pragma unroll
    for (int r = 0; r < 8; r++){
      float4 a4 = *(const float4*)(arow + (size_t)r * lda + kc);
#pragma unroll
      for (int q = 0; q < 4; q++)
        acc[r][q] = fmaf(w4[q].x, a4.x, fmaf(w4[q].y, a4.y,
                    fmaf(w4[q].z, a4.z, fmaf(w4[q].w, a4.w, acc[r][q]))));
    }
  }
#pragma unroll
  for (int r = 0; r < 8; r++){
#pragma unroll
    for (int q = 0; q < 4; q++){
      float v = wave_sum(acc[r][q]);
      const int n = n0 + q;
      if (lane == 0 && n < nmax){
        float o = v + (bias ? bias[n] : 0.f);
        if (relu) o = fmaxf(o, 0.f);
        C[(size_t)(m0 + r) * ldc + n] = o;
      }
    }
  }
}

// ---------------- cf = relu(Wp @ pf + bp), one wave per output row -----------
__global__ __launch_bounds__(256) void cf_kernel(
    const float* __restrict__ Wp, const float* __restrict__ pf,
    const float* __restrict__ bp, float* __restrict__ feats, int* __restrict__ flag)
{
  if (blockIdx.x == 0 && threadIdx.x == 0) *flag = 0;
  const int lane = threadIdx.x & 63, wid = threadIdx.x >> 6;
  const int n = (blockIdx.x << 2) + wid;            // 0..65535
  const float4* row = (const float4*)(Wp + (size_t)n * 512);
  const float4* p   = (const float4*)pf;
  float4 w0 = row[lane*2], w1 = row[lane*2+1];
  float4 p0 = p[lane*2],  p1 = p[lane*2+1];
  float v = wave_sum(dot8(w0, w1, p0, p1));
  if (lane == 0){
    float r = fmaxf(v + bp[n], 0.f);
    feats[(size_t)(n >> 9) * 1536 + (n & 511)] = r;   // cf -> feats cols [0,512)
  }
}

// ---------------- Wf3 (Wop cols 1024:1536) -> bf16 --------------------------
__global__ __launch_bounds__(256) void wconv_kernel(
    const float* __restrict__ Wop, u16* __restrict__ wfb)
{
  const int t = blockIdx.x * 256 + threadIdx.x;     // 0..65535
  const int e = t * 8;                              // elem in [2][512][512]
  const int it = e >> 18;
  const int rem = e & 262143;
  const int h = rem >> 9, k = rem & 511;
  const float* src = Wop + (size_t)it*788480 + (size_t)h*1540 + 1024 + k;
  float4 v0 = ((const float4*)src)[0];
  float4 v1 = ((const float4*)src)[1];
  union { u16 u[8]; uint4 q4; } o;
  o.u[0]=f2bf(v0.x); o.u[1]=f2bf(v0.y); o.u[2]=f2bf(v0.z); o.u[3]=f2bf(v0.w);
  o.u[4]=f2bf(v1.x); o.u[5]=f2bf(v1.y); o.u[6]=f2bf(v1.z); o.u[7]=f2bf(v1.w);
  *(uint4*)(wfb + e) = o.q4;
}

// ---------------- P/Q + it0 A/B (4 slabs, shared A=cf) + exists -------------
__global__ __launch_bounds__(256) void gemmPQAB(
    const float* __restrict__ feats,
    const float* __restrict__ Wel, const float* __restrict__ bel,
    const float* __restrict__ Wop, const float* __restrict__ bop,
    const float* __restrict__ We,  const float* __restrict__ be,
    float* __restrict__ P, float* __restrict__ Q,
    float* __restrict__ wsA, float* __restrict__ wsB,
    float* __restrict__ out_ex, float* __restrict__ exw)
{
  const int lane = threadIdx.x & 63, wid = threadIdx.x >> 6;
  const int bx = blockIdx.x, m0 = blockIdx.y * 8;
  if (bx < 128){
    const int n0 = (bx*4 + wid)*4;
    const int slab = n0 >> 9, nl = n0 & 511;
    const float* W; int ldw; const float* bias; float* C;
    switch (slab){
      case 0:  W = Wel;       ldw = 1024; bias = bel; C = P;   break;
      case 1:  W = Wel + 512; ldw = 1024; bias = 0;   C = Q;   break;
      case 2:  W = Wop;       ldw = 1540; bias = bop; C = wsA; break;
      default: W = Wop + 512; ldw = 1540; bias = 0;   C = wsB; break;
    }
    gemm_unit(feats, 1536, W, ldw, bias, C, 512, m0, nl, 512, 512, false, lane);
  } else {
    const float4* w = (const float4*)We;
    float4 w0 = w[lane*2], w1 = w[lane*2+1];
#pragma unroll
    for (int r = 0; r < 2; r++){
      const int m = m0 + wid*2 + r;
      const float4* a = (const float4*)(feats + (size_t)m*1536);
      float v = wave_sum(dot8(a[lane*2], a[lane*2+1], w0, w1));
      if (lane == 0){ float o = v + be[0]; out_ex[m] = o; exw[m] = o; }
    }
  }
}

// ---------------- el (bf16) + eel (f32) + has_edges; one wave per (i,j) ------
__global__ __launch_bounds__(256) void el_kernel(
    const float* __restrict__ P, const float* __restrict__ Q,
    const float* __restrict__ Wee, const float* __restrict__ bee,
    const float* __restrict__ ex,
    u16* __restrict__ elb, float* __restrict__ eelOut, int* __restrict__ flag)
{
  const int lane = threadIdx.x & 63, wid = threadIdx.x >> 6;
  const int row = (blockIdx.x << 2) + wid;          // 0..16383
  const int i = row >> 7, j = row & 127;
  const int k0 = lane << 3;
  float4 p0 = *(const float4*)(P + (size_t)i*512 + k0);
  float4 p1 = *(const float4*)(P + (size_t)i*512 + k0 + 4);
  float4 q0 = *(const float4*)(Q + (size_t)j*512 + k0);
  float4 q1 = *(const float4*)(Q + (size_t)j*512 + k0 + 4);
  float e[8];
  e[0]=fmaxf(p0.x+q0.x,0.f); e[1]=fmaxf(p0.y+q0.y,0.f);
  e[2]=fmaxf(p0.z+q0.z,0.f); e[3]=fmaxf(p0.w+q0.w,0.f);
  e[4]=fmaxf(p1.x+q1.x,0.f); e[5]=fmaxf(p1.y+q1.y,0.f);
  e[6]=fmaxf(p1.z+q1.z,0.f); e[7]=fmaxf(p1.w+q1.w,0.f);
  union { u16 u[8]; uint4 q4; } o;
#pragma unroll
  for (int c = 0; c < 8; c++) o.u[c] = f2bf(e[c]);
  *(uint4*)(elb + (size_t)row*512 + k0) = o.q4;
  float acc[4];
#pragma unroll
  for (int t = 0; t < 4; t++){
    float4 w0 = *(const float4*)(Wee + t*512 + k0);
    float4 w1 = *(const float4*)(Wee + t*512 + k0 + 4);
    acc[t] = wave_sum(e[0]*w0.x + e[1]*w0.y + e[2]*w0.z + e[3]*w0.w
                    + e[4]*w1.x + e[5]*w1.y + e[6]*w1.z + e[7]*w1.w);
  }
  if (lane == 0){
    float4 r = make_float4(acc[0]+bee[0], acc[1]+bee[1], acc[2]+bee[2], acc[3]+bee[3]);
    *(float4*)(eelOut + (size_t)row*4) = r;
    if ((ex[i] > 0.f) && (ex[j] > 0.f) &&
        (r.x > 0.f || r.y > 0.f || r.z > 0.f || r.w > 0.f))
      atomicOr(flag, 1);
  }
}

// ---------------- fused E-GEMM + msg + masked max per iteration -------------
// 1024 blocks: tile 128j x 64h, BK=64, dbuf, 50KB LDS -> ~3 blocks/CU.
// XCD map: bid&7 = xcd; each XCD owns 16 i-panels x 8 h-tiles (L2 reuse).
__global__ __launch_bounds__(256, 3) void iter_kernel(
    const u16* __restrict__ el, const u16* __restrict__ wfb,
    const float* __restrict__ Aterm, const float* __restrict__ Bterm,
    const float* __restrict__ eel, const float* __restrict__ ex,
    const float* __restrict__ wopWt,      // Wop + it*788480 (Wt cols 1536..)
    const int* __restrict__ flag,
    float* __restrict__ feats, int it)
{
  __shared__ u16 tile[2][12288];    // per buf: A 128x64 bf16 (16KB) + B 64x64 (8KB)
  __shared__ float smax[4][64];
  const int tid = threadIdx.x;
  const int lane = tid & 63, wid = tid >> 6;
  const int bid = blockIdx.x;
  const int xcd = bid & 7, loc = bid >> 3;
  const int i   = xcd*16 + (loc & 15);
  const int hc0 = (loc >> 4) << 6;

  // staging: 6 chunks/thread/step (A:4, B:2), 16B each; LDS linear,
  // global col-slot pre-swizzled: cb = s ^ (r&7)  (8 slots of 16B per 128B row).
  const u16* src[6]; int dst[6];
#pragma unroll
  for (int rd = 0; rd < 6; rd++){
    int c = tid + 256*rd;
    if (c < 1024){
      int r = c >> 3, s = c & 7, cb = s ^ (r & 7);
      src[rd] = el + (size_t)(i*128 + r)*512 + (cb << 3);
      dst[rd] = c << 3;
    } else {
      int c2 = c - 1024;
      int r = c2 >> 3, s = c2 & 7, cb = s ^ (r & 7);
      src[rd] = wfb + (size_t)(hc0 + r)*512 + (cb << 3);
      dst[rd] = 8192 + (c2 << 3);
    }
  }

  const int slog = lane >> 4;
  int byteA[2][2], byteB[2][4];
#pragma unroll
  for (int k2 = 0; k2 < 2; k2++){
#pragma unroll
    for (int fa = 0; fa < 2; fa++){
      int ra = wid*32 + fa*16 + (lane & 15);
      byteA[k2][fa] = ra*128 + (((k2*4 + slog) ^ (ra & 7)) << 4);
    }
#pragma unroll
    for (int f = 0; f < 4; f++){
      int rb = f*16 + (lane & 15);
      byteB[k2][f] = 16384 + rb*128 + (((k2*4 + slog) ^ (rb & 7)) << 4);
    }
  }

  f32x4 acc[2][4] = {};

  auto stage = [&](int buf, int ks){
    const int k0 = ks << 6;
#pragma unroll
    for (int rd = 0; rd < 6; rd++)
      gload_lds16(src[rd] + k0, &tile[buf][dst[rd]]);
  };

  stage(0, 0);
  __syncthreads();
  for (int ks = 0; ks < 8; ks++){
    const int cur = ks & 1;
    if (ks < 7) stage(cur ^ 1, ks + 1);
    const char* base = (const char*)&tile[cur][0];
#pragma unroll
    for (int k2 = 0; k2 < 2; k2++){
      bf16x8 a[2], b[4];
#pragma unroll
      for (int fa = 0; fa < 2; fa++) a[fa] = *(const bf16x8*)(base + byteA[k2][fa]);
#pragma unroll
      for (int f = 0; f < 4; f++)   b[f]  = *(const bf16x8*)(base + byteB[k2][f]);
#pragma unroll
      for (int fa = 0; fa < 2; fa++)
#pragma unroll
        for (int f = 0; f < 4; f++)
          acc[fa][f] = __builtin_amdgcn_mfma_f32_16x16x32_bf16(a[fa], b[f], acc[fa][f], 0, 0, 0);
    }
    __syncthreads();
  }

  // epilogue: msg = relu(pre + e0*Wt), masked max over (j,t)
  const bool mi = ex[i] > 0.f;
  float Ah[4]; float4 wt[4]; int hg[4];
#pragma unroll
  for (int f = 0; f < 4; f++){
    hg[f] = hc0 + f*16 + (lane & 15);
    Ah[f] = Aterm[i*512 + hg[f]];
    wt[f] = *(const float4*)(wopWt + (size_t)hg[f]*1540 + 1536);
  }
  float tm[4] = {0.f, 0.f, 0.f, 0.f};
#pragma unroll
  for (int fa = 0; fa < 2; fa++){
    const int j0 = wid*32 + fa*16 + slog*4;
#pragma unroll
    for (int r = 0; r < 4; r++){
      const int j = j0 + r;
      float4 e4 = *(const float4*)(eel + (size_t)(i*128 + j)*4);
      const bool mj = mi && (ex[j] > 0.f);
      const bool c0 = mj && (e4.x > 0.f), c1 = mj && (e4.y > 0.f);
      const bool c2 = mj && (e4.z > 0.f), c3 = mj && (e4.w > 0.f);
#pragma unroll
      for (int f = 0; f < 4; f++){
        float val = acc[fa][f][r] + Ah[f] + Bterm[(size_t)j*512 + hg[f]];
        if (c0) tm[f] = fmaxf(tm[f], val + e4.x*wt[f].x);
        if (c1) tm[f] = fmaxf(tm[f], val + e4.y*wt[f].y);
        if (c2) tm[f] = fmaxf(tm[f], val + e4.z*wt[f].z);
        if (c3) tm[f] = fmaxf(tm[f], val + e4.w*wt[f].w);
      }
    }
  }
#pragma unroll
  for (int f = 0; f < 4; f++){
    float v = tm[f];
    v = fmaxf(v, __shfl_xor(v, 16));
    v = fmaxf(v, __shfl_xor(v, 32));
    if (lane < 16) smax[wid][f*16 + lane] = v;
  }
  __syncthreads();
  if (tid < 64){
    const float v = fmaxf(fmaxf(smax[0][tid], smax[1][tid]),
                          fmaxf(smax[2][tid], smax[3][tid]));
    const int hgl = hc0 + tid;
    const float prev = feats[(size_t)i*1536 + it*512 + hgl];
    feats[(size_t)i*1536 + 512 + it*512 + hgl] = (*flag) ? v : prev;
  }
}

// ---------------- gemm4: dual slab, per-slab relu/ldc ------------------------
template<bool RA, bool RB>
__global__ __launch_bounds__(256) void gemm4(
    const float* __restrict__ A, int lda,
    const float* __restrict__ Wa, const float* __restrict__ Wb,
    int ldw, int Nsplit,
    const float* __restrict__ biasA, const float* __restrict__ biasB,
    float* __restrict__ Ca, float* __restrict__ Cb, int ldcA, int ldcB,
    int N, int K)
{
  const int lane = threadIdx.x & 63, wid = threadIdx.x >> 6;
  const int n0 = (blockIdx.x * 4 + wid) * 4;
  const int m0 = blockIdx.y * 8;
  const float* wrow[4];
#pragma unroll
  for (int q = 0; q < 4; q++){
    int n = n0 + q;
    int nn = n; const float* W = Wa;
    if (n >= Nsplit){ nn = n - Nsplit; W = Wb; }
    if (n >= N){ nn = 0; W = Wa; }
    wrow[q] = W + (size_t)nn * ldw + lane * 4;
  }
  const float* arow = A + (size_t)m0 * lda + lane * 4;
  float acc[8][4] = {};
  for (int kc = 0; kc < K; kc += 256){
    float4 w4[4];
#pragma unroll
    for (int q = 0; q < 4; q++) w4[q] = *(const float4*)(wrow[q] + kc);
#pragma unroll
    for (int r = 0; r < 8; r++){
      float4 a4 = *(const float4*)(arow + (size_t)r * lda + kc);
#pragma unroll
      for (int q = 0; q < 4; q++)
        acc[r][q] = fmaf(w4[q].x, a4.x, fmaf(w4[q].y, a4.y,
                    fmaf(w4[q].z, a4.z, fmaf(w4[q].w, a4.w, acc[r][q]))));
    }
  }
#pragma unroll
  for (int r = 0; r < 8; r++){
#pragma unroll
    for (int q = 0; q < 4; q++){
      float v = wave_sum(acc[r][q]);
      const int n = n0 + q;
      if (lane == 0 && n < N){
        const bool sb = n >= Nsplit;
        const float* bs = sb ? biasB : biasA;
        float o = v + (bs ? bs[sb ? n - Nsplit : n] : 0.f);
        if (sb ? RB : RA) o = fmaxf(o, 0.f);
        if (sb) Cb[(size_t)(m0 + r) * ldcB + (n - Nsplit)] = o;
        else    Ca[(size_t)(m0 + r) * ldcA + n] = o;
      }
    }
  }
}

// ---------------------------------------------------------------------------
extern "C" void kernel_launch(void* const* d_in, const int* in_sizes, int n_in,
                              void* d_out, int out_size, void* d_ws, size_t ws_size,
                              hipStream_t stream)
{
  const float* pf   = (const float*)d_in[0];
  const float* Wp   = (const float*)d_in[1];
  const float* bp   = (const float*)d_in[2];
  const float* We   = (const float*)d_in[3];
  const float* be   = (const float*)d_in[4];
  const float* Wsem = (const float*)d_in[5];
  const float* bsem = (const float*)d_in[6];
  const float* Wel  = (const float*)d_in[7];
  const float* bel  = (const float*)d_in[8];
  const float* Wee  = (const float*)d_in[9];
  const float* bee  = (const float*)d_in[10];
  const float* Wop  = (const float*)d_in[11];
  const float* bop  = (const float*)d_in[12];
  const float* Wc   = (const float*)d_in[13];
  const float* bc   = (const float*)d_in[14];
  const float* Wc2  = (const float*)d_in[15];
  const float* bc2  = (const float*)d_in[16];

  float* out      = (float*)d_out;
  float* out_cf   = out;             // [128,512]
  float* out_sem  = out + 65536;     // [128,50]
  float* out_ex   = out + 71936;     // [128]
  float* out_eel  = out + 72064;     // [128,128,4]

  char* ws = (char*)d_ws;
  u16*   elb   = (u16*)ws;                                // 16 MB bf16 el
  float* feats = (float*)(ws + 16777216);                 // [128][1536]
  float* P     = feats + 196608;                          // [128][512]
  float* Q     = P + 65536;
  float* wsA   = Q + 65536;
  float* wsB   = wsA + 65536;
  float* wsH   = wsB + 65536;
  float* exw   = wsH + 65536;                             // [128]
  int*   flag  = (int*)(exw + 160);
  u16*   wfb   = (u16*)(flag + 64);                       // [2][512][512] bf16

  cf_kernel<<<16384, 256, 0, stream>>>(Wp, pf, bp, feats, flag);
  wconv_kernel<<<256, 256, 0, stream>>>(Wop, wfb);
  gemmPQAB<<<dim3(129, 16), 256, 0, stream>>>(feats, Wel, bel, Wop, bop, We, be,
                                              P, Q, wsA, wsB, out_ex, exw);
  el_kernel<<<4096, 256, 0, stream>>>(P, Q, Wee, bee, exw, elb, out_eel, flag);

  for (int it = 0; it < 2; it++){
    const float* Wit = Wop + (size_t)it * 788480;
    if (it == 1)
      gemm4<false,false><<<dim3(64, 16), 256, 0, stream>>>(
          feats + 512, 1536, Wit, Wit + 512, 1540, 512,
          bop + 512, nullptr, wsA, wsB, 512, 512, 1024, 512);
    iter_kernel<<<1024, 256, 0, stream>>>(elb, wfb + it*262144, wsA, wsB,
                                          out_eel, exw, Wit, flag, feats, it);
  }
  // head: h = relu(feats @ Wc.T + bc)
  gemm4<true,true><<<dim3(32, 16), 256, 0, stream>>>(
      feats, 1536, Wc, Wc, 1536, 512, bc, nullptr,
      wsH, wsH, 512, 512, 512, 1536);
  // sem (no relu) + out_cf (relu) merged: N = 50 + 512
  gemm4<false,true><<<dim3(36, 16), 256, 0, stream>>>(
      wsH, 512, Wsem, Wc2, 512, 50, bsem, bc2,
      out_sem, out_cf, 50, 512, 562, 512);
}